// Round 1
// baseline (381.218 us; speedup 1.0000x reference)
//
#include <hip/hip_runtime.h>
#include <hip/hip_bf16.h>

#define Bn 4
#define Cn 64
#define Hn 128
#define Wn 128
#define On 64
#define DGn 2
#define Cgn 32
#define HWn (Hn*Wn)

// ws layout (floats):
//   off   : [B][36][H][W]   @ 0                (9,437,184 B)
//   wtdef : [2][9][32][64]  @ OFF_FLOATS       (147,456 B)
//   wtoff : [64][9][36]     @ +WTDEF_FLOATS    (82,944 B)
#define OFF_FLOATS   (Bn*36*HWn)
#define WTDEF_FLOATS (2*9*32*64)
#define WTOFF_FLOATS (64*9*36)

// Transpose weights so the wave-uniform inner loops read CONTIGUOUS scalar data.
__global__ __launch_bounds__(256) void prep_weights(const float* __restrict__ w_off,
                                                    const float* __restrict__ w_def,
                                                    float* __restrict__ wtdef,
                                                    float* __restrict__ wtoff) {
  int t = blockIdx.x * 256 + threadIdx.x;
  if (t < WTDEF_FLOATS) {
    // dst [g][k][c][o] = w_def[o][g*32+c][k]
    int o = t & 63;
    int c = (t >> 6) & 31;
    int r = t >> 11;         // g*9 + k
    int k = r % 9;
    int g = r / 9;
    wtdef[t] = w_def[(o * Cn + g * Cgn + c) * 9 + k];
  }
  if (t < WTOFF_FLOATS) {
    // dst [c][k][j] = w_off[j][c][k]
    int j = t % 36;
    int k = (t / 36) % 9;
    int c = t / 324;
    wtoff[t] = w_off[(j * Cn + c) * 9 + k];
  }
}

// Offset conv: 3x3, 64 -> 36 channels, pad 1. One thread per pixel, acc[36].
__global__ __launch_bounds__(256) void offs_conv(const float* __restrict__ x,
                                                 const float* __restrict__ wtoff,
                                                 float* __restrict__ off) {
  const int t = blockIdx.x * 256 + threadIdx.x;
  const int w = t & (Wn - 1);
  const int h = (t >> 7) & (Hn - 1);
  const int b = t >> 14;
  const int pix = h * Wn + w;

  float acc[36];
#pragma unroll
  for (int j = 0; j < 36; ++j) acc[j] = 0.f;

  const float* xb = x + b * Cn * HWn;

  for (int c = 0; c < Cn; ++c) {
    const float* xc = xb + c * HWn;
    float xv[9];
#pragma unroll
    for (int kh = 0; kh < 3; ++kh) {
#pragma unroll
      for (int kw = 0; kw < 3; ++kw) {
        int hh = h + kh - 1, ww = w + kw - 1;
        bool v = (hh >= 0) && (hh < Hn) && (ww >= 0) && (ww < Wn);
        int hc = min(max(hh, 0), Hn - 1);
        int wc = min(max(ww, 0), Wn - 1);
        float val = xc[hc * Wn + wc];     // clamped address: always in-bounds
        xv[kh * 3 + kw] = v ? val : 0.f;
      }
    }
    const float* wc = wtoff + c * 324;    // [k][j], j contiguous -> s_load runs
#pragma unroll
    for (int k = 0; k < 9; ++k) {
#pragma unroll
      for (int j = 0; j < 36; ++j)
        acc[j] = fmaf(xv[k], wc[k * 36 + j], acc[j]);
    }
  }

  float* op = off + b * 36 * HWn + pix;
#pragma unroll
  for (int j = 0; j < 36; ++j) op[j * HWn] = acc[j];
}

// Main deformable conv. One thread per pixel, acc[64] over output channels.
__global__ __launch_bounds__(256) void deform_main(const float* __restrict__ x,
                                                   const float* __restrict__ wtdef,
                                                   const float* __restrict__ off,
                                                   float* __restrict__ out) {
  const int t = blockIdx.x * 256 + threadIdx.x;
  const int w = t & (Wn - 1);
  const int h = (t >> 7) & (Hn - 1);
  const int b = t >> 14;
  const int pix = h * Wn + w;

  const float* offp = off + b * 36 * HWn + pix;

  float acc[On];
#pragma unroll
  for (int o = 0; o < On; ++o) acc[o] = 0.f;

  for (int g = 0; g < DGn; ++g) {
    const float* xg = x + (b * Cn + g * Cgn) * HWn;
    for (int k = 0; k < 9; ++k) {
      // offsets: channel layout (g, k, {dy,dx})
      float ody = offp[(g * 18 + k * 2 + 0) * HWn];
      float odx = offp[(g * 18 + k * 2 + 1) * HWn];
      float py = ody + (float)(h + k / 3 - 1);
      float px = odx + (float)(w + k % 3 - 1);
      float fy = floorf(py), fx = floorf(px);
      int y0 = (int)fy, x0 = (int)fx;
      float dy = py - fy, dx = px - fx;

      bool vy0 = (y0 >= 0) && (y0 < Hn);
      bool vy1 = (y0 >= -1) && (y0 < Hn - 1);
      bool vx0 = (x0 >= 0) && (x0 < Wn);
      bool vx1 = (x0 >= -1) && (x0 < Wn - 1);
      float omdy = 1.f - dy, omdx = 1.f - dx;
      // fold per-corner validity into the bilinear weights (ref: val*valid)
      float w00 = (vy0 && vx0) ? omdy * omdx : 0.f;
      float w01 = (vy0 && vx1) ? omdy * dx   : 0.f;
      float w10 = (vy1 && vx0) ? dy * omdx   : 0.f;
      float w11 = (vy1 && vx1) ? dy * dx     : 0.f;

      int iy0 = min(max(y0, 0), Hn - 1), iy1 = min(max(y0 + 1, 0), Hn - 1);
      int ix0 = min(max(x0, 0), Wn - 1), ix1 = min(max(x0 + 1, 0), Wn - 1);
      int b00 = iy0 * Wn + ix0, b01 = iy0 * Wn + ix1;
      int b10 = iy1 * Wn + ix0, b11 = iy1 * Wn + ix1;

      const float* wgk = wtdef + (g * 9 + k) * Cgn * On;  // [c][o], o contiguous
      for (int c = 0; c < Cgn; ++c) {
        const float* xc = xg + c * HWn;
        float val =       w00 * xc[b00];
        val = fmaf(w01, xc[b01], val);
        val = fmaf(w10, xc[b10], val);
        val = fmaf(w11, xc[b11], val);
        const float* wv = wgk + c * On;
#pragma unroll
        for (int o = 0; o < On; ++o)
          acc[o] = fmaf(val, wv[o], acc[o]);   // wv[o] wave-uniform -> s_load
      }
    }
  }

  float* outp = out + b * On * HWn + pix;
#pragma unroll
  for (int o = 0; o < On; ++o) outp[o * HWn] = acc[o];
}

extern "C" void kernel_launch(void* const* d_in, const int* in_sizes, int n_in,
                              void* d_out, int out_size, void* d_ws, size_t ws_size,
                              hipStream_t stream) {
  const float* x     = (const float*)d_in[0];
  const float* w_off = (const float*)d_in[1];
  const float* w_def = (const float*)d_in[2];
  float* out = (float*)d_out;

  float* ws    = (float*)d_ws;
  float* off   = ws;
  float* wtdef = ws + OFF_FLOATS;
  float* wtoff = wtdef + WTDEF_FLOATS;

  prep_weights<<<(WTDEF_FLOATS + 255) / 256, 256, 0, stream>>>(w_off, w_def, wtdef, wtoff);
  offs_conv<<<(Bn * HWn) / 256, 256, 0, stream>>>(x, wtoff, off);
  deform_main<<<(Bn * HWn) / 256, 256, 0, stream>>>(x, wtdef, off, out);
}